// Round 5
// baseline (755.238 us; speedup 1.0000x reference)
//
#include <hip/hip_runtime.h>
#include <math.h>

#define V 50257
#define H 1024
#define E 512
#define L 128
#define HE 1536
#define NB 1024            // mega-kernel grid (must ALL be co-resident)
#define NW (NB * 4)        // 4096 waves
#define ROWS_PW 13         // ceil(V / NW)

// ws float layout
#define WS_DECRAW 0        // 1536: [embed(512) | attn_out(1024)]
#define WS_DECIN  1536     // 1024
#define WS_HNEW   2560     // 1024
#define WS_ALOGIT 3584     // 128
#define WS_PAIRS  3712     // 2*NB
#define WS_CNT    5760     // 5*64 barrier counters (as uint)

__device__ __forceinline__ float wave_reduce_sum(float v) {
    #pragma unroll
    for (int off = 32; off > 0; off >>= 1) v += __shfl_xor(v, off, 64);
    return v;
}

// device-scope grid barrier: 64 spread counters, 16 arrivals each (NB=1024)
__device__ __forceinline__ void gbar(unsigned* cnt, int which) {
    __syncthreads();                      // all block stores drained (vmcnt 0)
    if (threadIdx.x == 0) {
        __threadfence();                  // release: writeback XCD L2 to MALL
        __hip_atomic_fetch_add(&cnt[which * 64 + (blockIdx.x & 63)], 1u,
                               __ATOMIC_RELEASE, __HIP_MEMORY_SCOPE_AGENT);
    }
    if (threadIdx.x < 64) {
        while (__hip_atomic_load(&cnt[which * 64 + threadIdx.x],
                                 __ATOMIC_RELAXED, __HIP_MEMORY_SCOPE_AGENT)
               < (unsigned)(NB / 64)) {
            __builtin_amdgcn_s_sleep(32);
        }
    }
    __syncthreads();
    __threadfence();                      // acquire: invalidate stale XCD L2
}

__global__ void k_reset(unsigned* cnt) {
    const int g = blockIdx.x * 256 + threadIdx.x;
    if (g < 5 * 64) cnt[g] = 0u;
}

__global__ __launch_bounds__(256, 4)
void k_mega(const int* __restrict__ tok_p, const float* __restrict__ h0,
            const float* __restrict__ c0, const float* __restrict__ enc,
            const float* __restrict__ emb, const float* __restrict__ attn_W,
            const float* __restrict__ attn_b, const float* __restrict__ a2d_W,
            const float* __restrict__ a2d_b, const float* __restrict__ W_ih,
            const float* __restrict__ W_hh, const float* __restrict__ b_ih,
            const float* __restrict__ b_hh, const float* __restrict__ out_W,
            const float* __restrict__ out_b,
            float* __restrict__ logits, float* __restrict__ out_h,
            float* __restrict__ out_c, float* __restrict__ out_attnw,
            float* __restrict__ ws, unsigned* __restrict__ cnt) {
    __shared__ __align__(16) float s_in[HE];
    __shared__ float s_part[8];
    __shared__ float s_wn[L];
    __shared__ float s_acc[4][64];
    __shared__ float s_g[4];
    __shared__ float sm[256], ss[256];

    const int tid = threadIdx.x, lane = tid & 63, w = tid >> 6;
    const int bid = blockIdx.x;

    // ---- Phase 0: attention logits (blocks 0..127); block 0 writes embed --
    if (bid < 128) {
        const int tokv = tok_p[0];
        for (int k = tid; k < HE; k += 256) {
            float v = (k < E) ? emb[(size_t)tokv * E + k] : h0[k - E];
            s_in[k] = v;
            if (bid == 0 && k < E) ws[WS_DECRAW + k] = v;
        }
        __syncthreads();
        const float4* s4 = (const float4*)s_in;
        const float4* w4 = (const float4*)(attn_W + (size_t)bid * HE);
        float acc;
        {
            float4 a = s4[lane + (w << 6)];
            float4 b = w4[lane + (w << 6)];
            acc = a.x * b.x + a.y * b.y + a.z * b.z + a.w * b.w;
        }
        if (w < 2) {
            const int c = w + 4;
            float4 a = s4[lane + (c << 6)];
            float4 b = w4[lane + (c << 6)];
            acc += a.x * b.x + a.y * b.y + a.z * b.z + a.w * b.w;
        }
        acc = wave_reduce_sum(acc);
        if (lane == 0) s_part[w] = acc;
        __syncthreads();
        if (tid == 0)
            ws[WS_ALOGIT + bid] = s_part[0] + s_part[1] + s_part[2] + s_part[3]
                                  + attn_b[bid];
    }
    gbar(cnt, 0);

    // ---- Phase 1: softmax + attn_out (blocks 0..15) ------------------------
    if (bid < 16) {
        if (tid < L) s_wn[tid] = ws[WS_ALOGIT + tid];
        __syncthreads();
        float mx = -1e30f;
        #pragma unroll
        for (int l = 0; l < L; ++l) mx = fmaxf(mx, s_wn[l]);
        float sum = 0.f;
        #pragma unroll
        for (int l = 0; l < L; ++l) sum += __expf(s_wn[l] - mx);
        __syncthreads();
        if (tid < L) {
            float wn = __expf(s_wn[tid] - mx) / sum;
            s_wn[tid] = wn;
            if (bid == 0) out_attnw[tid] = wn;
        }
        __syncthreads();
        const int j = bid * 64 + lane;
        float acc = 0.f;
        #pragma unroll
        for (int li = 0; li < 32; ++li) {
            const int l = (w << 5) + li;
            acc = fmaf(s_wn[l], enc[l * H + j], acc);
        }
        s_acc[w][lane] = acc;
        __syncthreads();
        if (tid < 64)
            ws[WS_DECRAW + E + bid * 64 + tid] =
                s_acc[0][tid] + s_acc[1][tid] + s_acc[2][tid] + s_acc[3][tid];
    }
    gbar(cnt, 1);

    // ---- Phase 2: dec_in = relu(a2d_W @ dec_raw + b) (all blocks, row=bid) -
    {
        const float4* x4 = (const float4*)(ws + WS_DECRAW);
        const float4* w4 = (const float4*)(a2d_W + (size_t)bid * HE);
        float acc;
        {
            float4 a = x4[lane + (w << 6)];
            float4 b = w4[lane + (w << 6)];
            acc = a.x * b.x + a.y * b.y + a.z * b.z + a.w * b.w;
        }
        if (w < 2) {
            const int c = w + 4;
            float4 a = x4[lane + (c << 6)];
            float4 b = w4[lane + (c << 6)];
            acc += a.x * b.x + a.y * b.y + a.z * b.z + a.w * b.w;
        }
        acc = wave_reduce_sum(acc);
        if (lane == 0) s_part[w] = acc;
        __syncthreads();
        if (tid == 0)
            ws[WS_DECIN + bid] = fmaxf(s_part[0] + s_part[1] + s_part[2]
                                        + s_part[3] + a2d_b[bid], 0.f);
    }
    gbar(cnt, 2);

    // ---- Phase 3: LSTM (all blocks, j = bid, wave = gate) ------------------
    {
        const float4* x4 = (const float4*)(ws + WS_DECIN);
        const float4* h4 = (const float4*)h0;
        const size_t r = (size_t)w * H + bid;
        const float4* wi4 = (const float4*)(W_ih + r * H);
        const float4* wh4 = (const float4*)(W_hh + r * H);
        float acc = 0.f;
        #pragma unroll
        for (int k = 0; k < 4; ++k) {
            float4 a = wi4[lane + (k << 6)];
            float4 x = x4[lane + (k << 6)];
            acc = fmaf(a.x, x.x, acc); acc = fmaf(a.y, x.y, acc);
            acc = fmaf(a.z, x.z, acc); acc = fmaf(a.w, x.w, acc);
            float4 b = wh4[lane + (k << 6)];
            float4 h = h4[lane + (k << 6)];
            acc = fmaf(b.x, h.x, acc); acc = fmaf(b.y, h.y, acc);
            acc = fmaf(b.z, h.z, acc); acc = fmaf(b.w, h.w, acc);
        }
        acc = wave_reduce_sum(acc);
        if (lane == 0) s_g[w] = acc;
        __syncthreads();
        if (tid == 0) {
            const int j = bid;
            float gi_ = s_g[0] + b_ih[j]         + b_hh[j];
            float gf  = s_g[1] + b_ih[H + j]     + b_hh[H + j];
            float gg  = s_g[2] + b_ih[2 * H + j] + b_hh[2 * H + j];
            float go  = s_g[3] + b_ih[3 * H + j] + b_hh[3 * H + j];
            float si = 1.f / (1.f + expf(-gi_));
            float sf = 1.f / (1.f + expf(-gf));
            float so = 1.f / (1.f + expf(-go));
            float cn = sf * c0[j] + si * tanhf(gg);
            float hn = so * tanhf(cn);
            out_c[j] = cn;
            out_h[j] = hn;
            ws[WS_HNEW + j] = hn;
        }
    }
    gbar(cnt, 3);

    // ---- Phase 4: vocab matvec + per-block online (max,sumexp) -------------
    {
        const int gw = (bid << 2) + w;            // 0..4095
        const float4* h4 = (const float4*)(ws + WS_HNEW);
        float4 hr[4];
        #pragma unroll
        for (int k = 0; k < 4; ++k) hr[k] = h4[lane + (k << 6)];
        float m = -1e30f, s = 0.f;
        #pragma unroll
        for (int i = 0; i < ROWS_PW; ++i) {
            const int v = gw + i * NW;
            if (v < V) {
                const float4* w4 = (const float4*)(out_W + (size_t)v * H);
                float acc = 0.f;
                #pragma unroll
                for (int k = 0; k < 4; ++k) {
                    float4 a = w4[lane + (k << 6)];
                    acc = fmaf(hr[k].x, a.x, acc); acc = fmaf(hr[k].y, a.y, acc);
                    acc = fmaf(hr[k].z, a.z, acc); acc = fmaf(hr[k].w, a.w, acc);
                }
                acc = wave_reduce_sum(acc);
                const float lv = acc + out_b[v];
                if (lane == 0) logits[v] = lv;
                const float mo = m;
                m = fmaxf(m, lv);
                s = s * __expf(mo - m) + __expf(lv - m);
            }
        }
        if (lane == 0) { sm[w] = m; ss[w] = s; }
        __syncthreads();
        if (tid == 0) {
            float M = sm[0], S = ss[0];
            #pragma unroll
            for (int i = 1; i < 4; ++i) {
                float Mn = fmaxf(M, sm[i]);
                S = S * __expf(M - Mn) + ss[i] * __expf(sm[i] - Mn);
                M = Mn;
            }
            ws[WS_PAIRS + 2 * bid]     = M;
            ws[WS_PAIRS + 2 * bid + 1] = S;
        }
    }
    gbar(cnt, 4);

    // ---- Phase 5: fold 1024 pairs (redundant per block), normalize ---------
    {
        float M = -1e30f, S = 0.f;
        #pragma unroll
        for (int i = 0; i < 4; ++i) {
            const int p = tid + (i << 8);         // 0..1023
            float m2 = ws[WS_PAIRS + 2 * p], s2 = ws[WS_PAIRS + 2 * p + 1];
            float Mn = fmaxf(M, m2);
            S = S * __expf(M - Mn) + s2 * __expf(m2 - Mn);
            M = Mn;
        }
        sm[tid] = M; ss[tid] = S;
        __syncthreads();
        for (int off = 128; off > 0; off >>= 1) {
            if (tid < off) {
                float m2 = sm[tid + off], s2 = ss[tid + off];
                float Mn = fmaxf(sm[tid], m2);
                ss[tid] = ss[tid] * __expf(sm[tid] - Mn) + s2 * __expf(m2 - Mn);
                sm[tid] = Mn;
            }
            __syncthreads();
        }
        const float C = sm[0] + logf(ss[0]);
        const int g = bid * 256 + tid;            // 262144 threads >= V
        if (g < V) logits[g] -= C;
    }
}

extern "C" void kernel_launch(void* const* d_in, const int* in_sizes, int n_in,
                              void* d_out, int out_size, void* d_ws, size_t ws_size,
                              hipStream_t stream) {
    const int*   tok    = (const int*)d_in[0];
    const float* h0     = (const float*)d_in[1];
    const float* c0     = (const float*)d_in[2];
    const float* enc    = (const float*)d_in[3];
    const float* emb    = (const float*)d_in[4];
    const float* attn_W = (const float*)d_in[5];
    const float* attn_b = (const float*)d_in[6];
    const float* a2d_W  = (const float*)d_in[7];
    const float* a2d_b  = (const float*)d_in[8];
    const float* W_ih   = (const float*)d_in[9];
    const float* W_hh   = (const float*)d_in[10];
    const float* b_ih   = (const float*)d_in[11];
    const float* b_hh   = (const float*)d_in[12];
    const float* out_W  = (const float*)d_in[13];
    const float* out_b  = (const float*)d_in[14];

    float* out        = (float*)d_out;
    float* ws         = (float*)d_ws;
    float* out_logits = out;                 // V
    float* out_h      = out + V;             // H
    float* out_c      = out + V + H;         // H
    float* out_attnw  = out + V + 2 * H;     // L
    unsigned* cnt     = (unsigned*)(ws + WS_CNT);

    k_reset<<<2, 256, 0, stream>>>(cnt);
    k_mega<<<NB, 256, 0, stream>>>(tok, h0, c0, enc, emb, attn_W, attn_b,
                                   a2d_W, a2d_b, W_ih, W_hh, b_ih, b_hh,
                                   out_W, out_b, out_logits, out_h, out_c,
                                   out_attnw, ws, cnt);
}

// Round 6
// 80.325 us; speedup vs baseline: 9.4023x; 9.4023x over previous
//
#include <hip/hip_runtime.h>
#include <math.h>

#define V 50257
#define H 1024
#define E 512
#define L 128
#define HE 1536
#define NBLK5 2048         // blocks for vocab matvec -> 8192 waves
#define VSTRIDE (NBLK5 * 4)

// ws float layout
#define WS_DECRAW 0        // 1536: [embed(512) | attn_out(1024)]
#define WS_DECIN  1536     // 1024: relu(a2d)
#define WS_HNEW   2560     // 1024: aligned copy of h_new
#define WS_GHH    3584     // 4096: W_hh @ h0 (gate-major)
#define WS_PAIRS  7680     // 2*NBLK5: (max, sumexp) per k_vocab block

__device__ __forceinline__ float wave_reduce_sum(float v) {
    #pragma unroll
    for (int off = 32; off > 0; off >>= 1) v += __shfl_xor(v, off, 64);
    return v;
}

// -------- K1: blocks 0..15 = full attention; blocks 16..1039 = W_hh@h0 ----
__global__ __launch_bounds__(256)
void k_attn_whh(const int* __restrict__ tok_p,
                const float* __restrict__ h0,
                const float* __restrict__ emb,
                const float* __restrict__ attn_W,
                const float* __restrict__ attn_b,
                const float* __restrict__ enc,
                const float* __restrict__ W_hh,
                float* __restrict__ out_attnw,
                float* __restrict__ ws) {
    const int tid = threadIdx.x, lane = tid & 63, w = tid >> 6;
    const int bid = blockIdx.x;

    if (bid >= 16) {
        // ---- ghh[g*H + j] = dot(W_hh[g*H + j], h0), j = bid-16, wave = g --
        const int j = bid - 16;                    // 0..1023
        const float4* h4 = (const float4*)h0;
        const float4* wh4 = (const float4*)(W_hh + ((size_t)w * H + j) * H);
        float acc = 0.f;
        #pragma unroll
        for (int k = 0; k < 4; ++k) {
            float4 b = wh4[lane + (k << 6)];
            float4 h = h4[lane + (k << 6)];
            acc = fmaf(b.x, h.x, acc); acc = fmaf(b.y, h.y, acc);
            acc = fmaf(b.z, h.z, acc); acc = fmaf(b.w, h.w, acc);
        }
        acc = wave_reduce_sum(acc);
        if (lane == 0) ws[WS_GHH + w * H + j] = acc;
        return;
    }

    // ---- attention: each of 16 blocks computes ALL 128 logits (L2-hot) ----
    __shared__ __align__(16) float s_in[HE];
    __shared__ float s_logit[L];
    __shared__ float s_wn[L];
    __shared__ float s_acc[4][64];
    const int tok = tok_p[0];
    for (int k = tid; k < HE; k += 256) {
        float v = (k < E) ? emb[(size_t)tok * E + k] : h0[k - E];
        s_in[k] = v;
        if (bid == 0 && k < E) ws[WS_DECRAW + k] = v;   // embed slice
    }
    __syncthreads();
    const float4* s4 = (const float4*)s_in;
    #pragma unroll
    for (int rr = 0; rr < 32; ++rr) {
        const int r = (rr << 2) + w;               // 0..127
        const float4* w4 = (const float4*)(attn_W + (size_t)r * HE);
        float acc = 0.f;
        #pragma unroll
        for (int c = 0; c < 6; ++c) {
            float4 a = s4[lane + (c << 6)];
            float4 b = w4[lane + (c << 6)];
            acc = fmaf(a.x, b.x, acc); acc = fmaf(a.y, b.y, acc);
            acc = fmaf(a.z, b.z, acc); acc = fmaf(a.w, b.w, acc);
        }
        acc = wave_reduce_sum(acc);
        if (lane == 0) s_logit[r] = acc + attn_b[r];
    }
    __syncthreads();
    // softmax over 128 (no max-subtraction: |logit| <~ 5, exp-safe in fp32)
    float sum = 0.f;
    #pragma unroll
    for (int l = 0; l < L; ++l) sum += __expf(s_logit[l]);
    const float inv = 1.f / sum;
    __syncthreads();
    if (tid < L) {
        float wn = __expf(s_logit[tid]) * inv;
        s_wn[tid] = wn;
        if (bid == 0) out_attnw[tid] = wn;
    }
    __syncthreads();
    // attn_out: 64 cols per block, wave w handles l in [w*32, w*32+32)
    const int j = bid * 64 + lane;
    float acc = 0.f;
    #pragma unroll
    for (int li = 0; li < 32; ++li) {
        const int l = (w << 5) + li;
        acc = fmaf(s_wn[l], enc[l * H + j], acc);
    }
    s_acc[w][lane] = acc;
    __syncthreads();
    if (tid < 64)
        ws[WS_DECRAW + E + bid * 64 + tid] =
            s_acc[0][tid] + s_acc[1][tid] + s_acc[2][tid] + s_acc[3][tid];
}

// -------- K2: dec_in = relu(dec_in_raw @ a2d_W.T + b). 1024 blocks x 384 --
__global__ void k_a2d(const float* __restrict__ a2d_W,
                      const float* __restrict__ a2d_b,
                      float* __restrict__ ws) {
    __shared__ float s_part[6];
    const int tid = threadIdx.x, lane = tid & 63, w = tid >> 6;
    const int r = blockIdx.x;                    // 0..1023
    const float4* x4 = (const float4*)(ws + WS_DECRAW);
    const float4* w4 = (const float4*)(a2d_W + (size_t)r * HE);
    float4 a = x4[lane + (w << 6)];
    float4 b = w4[lane + (w << 6)];
    float acc = a.x * b.x + a.y * b.y + a.z * b.z + a.w * b.w;
    acc = wave_reduce_sum(acc);
    if (lane == 0) s_part[w] = acc;
    __syncthreads();
    if (tid == 0) {
        float t = s_part[0] + s_part[1] + s_part[2] + s_part[3] + s_part[4] + s_part[5];
        ws[WS_DECIN + r] = fmaxf(t + a2d_b[r], 0.f);
    }
}

// -------- K3: LSTM. 1024 blocks x 256; W_ih half only, ghh precomputed ----
__global__ void k_lstm(const float* __restrict__ c0,
                       const float* __restrict__ W_ih,
                       const float* __restrict__ b_ih,
                       const float* __restrict__ b_hh,
                       float* __restrict__ out_h,
                       float* __restrict__ out_c,
                       float* __restrict__ ws) {
    __shared__ float s_g[4];
    const int tid = threadIdx.x, lane = tid & 63, w = tid >> 6;   // w = gate
    const int j = blockIdx.x;                                     // 0..1023
    const float4* x4 = (const float4*)(ws + WS_DECIN);
    const float4* wi4 = (const float4*)(W_ih + ((size_t)w * H + j) * H);
    float acc = 0.f;
    #pragma unroll
    for (int k = 0; k < 4; ++k) {
        float4 a = wi4[lane + (k << 6)];
        float4 x = x4[lane + (k << 6)];
        acc = fmaf(a.x, x.x, acc); acc = fmaf(a.y, x.y, acc);
        acc = fmaf(a.z, x.z, acc); acc = fmaf(a.w, x.w, acc);
    }
    acc = wave_reduce_sum(acc);
    if (lane == 0) s_g[w] = acc + ws[WS_GHH + w * H + j];
    __syncthreads();
    if (tid == 0) {
        float gi_ = s_g[0] + b_ih[j]         + b_hh[j];
        float gf  = s_g[1] + b_ih[H + j]     + b_hh[H + j];
        float gg  = s_g[2] + b_ih[2 * H + j] + b_hh[2 * H + j];
        float go  = s_g[3] + b_ih[3 * H + j] + b_hh[3 * H + j];
        float si = 1.f / (1.f + expf(-gi_));
        float sf = 1.f / (1.f + expf(-gf));
        float so = 1.f / (1.f + expf(-go));
        float cn = sf * c0[j] + si * tanhf(gg);
        float hn = so * tanhf(cn);
        out_c[j] = cn;
        out_h[j] = hn;
        ws[WS_HNEW + j] = hn;
    }
}

// -------- K4: vocab matvec, 2 rows in flight per wave ---------------------
__global__ void k_vocab(const float* __restrict__ out_W,
                        const float* __restrict__ out_b,
                        float* __restrict__ logits,
                        float* __restrict__ ws) {
    const int lane = threadIdx.x & 63;
    const int widx = threadIdx.x >> 6;
    const int gw = (blockIdx.x << 2) + widx;          // 0..8191
    const float4* h4 = (const float4*)(ws + WS_HNEW);
    float4 hr[4];
    #pragma unroll
    for (int k = 0; k < 4; ++k) hr[k] = h4[lane + (k << 6)];
    float m = -1e30f, s = 0.f;
    for (int v = gw; v < V; v += 2 * VSTRIDE) {
        const int v2 = v + VSTRIDE;
        const float4* w0 = (const float4*)(out_W + (size_t)v * H);
        float acc0 = 0.f, acc1 = 0.f;
        #pragma unroll
        for (int k = 0; k < 4; ++k) {
            float4 a = w0[lane + (k << 6)];
            acc0 = fmaf(hr[k].x, a.x, acc0); acc0 = fmaf(hr[k].y, a.y, acc0);
            acc0 = fmaf(hr[k].z, a.z, acc0); acc0 = fmaf(hr[k].w, a.w, acc0);
        }
        if (v2 < V) {
            const float4* w1 = (const float4*)(out_W + (size_t)v2 * H);
            #pragma unroll
            for (int k = 0; k < 4; ++k) {
                float4 a = w1[lane + (k << 6)];
                acc1 = fmaf(hr[k].x, a.x, acc1); acc1 = fmaf(hr[k].y, a.y, acc1);
                acc1 = fmaf(hr[k].z, a.z, acc1); acc1 = fmaf(hr[k].w, a.w, acc1);
            }
        }
        acc0 = wave_reduce_sum(acc0);
        float l0 = acc0 + out_b[v];
        if (lane == 0) logits[v] = l0;
        float mo = m;
        m = fmaxf(m, l0);
        s = s * __expf(mo - m) + __expf(l0 - m);
        if (v2 < V) {
            acc1 = wave_reduce_sum(acc1);
            float l1 = acc1 + out_b[v2];
            if (lane == 0) logits[v2] = l1;
            mo = m;
            m = fmaxf(m, l1);
            s = s * __expf(mo - m) + __expf(l1 - m);
        }
    }
    __shared__ float sm[4], ss[4];
    if (lane == 0) { sm[widx] = m; ss[widx] = s; }
    __syncthreads();
    if (threadIdx.x == 0) {
        float M = sm[0], S = ss[0];
        #pragma unroll
        for (int i = 1; i < 4; ++i) {
            float Mn = fmaxf(M, sm[i]);
            S = S * __expf(M - Mn) + ss[i] * __expf(sm[i] - Mn);
            M = Mn;
        }
        ws[WS_PAIRS + 2 * blockIdx.x]     = M;
        ws[WS_PAIRS + 2 * blockIdx.x + 1] = S;
    }
}

// -------- K5: fold partials + finalize log-softmax ------------------------
__global__ void k_final(float* __restrict__ logits,
                        const float* __restrict__ ws) {
    __shared__ float sm[256], ss[256];
    const int tid = threadIdx.x;
    float M = -1e30f, S = 0.f;
    for (int i = tid; i < NBLK5; i += 256) {
        float m2 = ws[WS_PAIRS + 2 * i], s2 = ws[WS_PAIRS + 2 * i + 1];
        float Mn = fmaxf(M, m2);
        S = S * __expf(M - Mn) + s2 * __expf(m2 - Mn);
        M = Mn;
    }
    sm[tid] = M; ss[tid] = S;
    __syncthreads();
    for (int off = 128; off > 0; off >>= 1) {
        if (tid < off) {
            float m2 = sm[tid + off], s2 = ss[tid + off];
            float Mn = fmaxf(sm[tid], m2);
            ss[tid] = ss[tid] * __expf(sm[tid] - Mn) + s2 * __expf(m2 - Mn);
            sm[tid] = Mn;
        }
        __syncthreads();
    }
    const float C = sm[0] + logf(ss[0]);
    for (int v = blockIdx.x * 256 + tid; v < V; v += gridDim.x * 256)
        logits[v] -= C;
}

extern "C" void kernel_launch(void* const* d_in, const int* in_sizes, int n_in,
                              void* d_out, int out_size, void* d_ws, size_t ws_size,
                              hipStream_t stream) {
    const int*   tok    = (const int*)d_in[0];
    const float* h0     = (const float*)d_in[1];
    const float* c0     = (const float*)d_in[2];
    const float* enc    = (const float*)d_in[3];
    const float* emb    = (const float*)d_in[4];
    const float* attn_W = (const float*)d_in[5];
    const float* attn_b = (const float*)d_in[6];
    const float* a2d_W  = (const float*)d_in[7];
    const float* a2d_b  = (const float*)d_in[8];
    const float* W_ih   = (const float*)d_in[9];
    const float* W_hh   = (const float*)d_in[10];
    const float* b_ih   = (const float*)d_in[11];
    const float* b_hh   = (const float*)d_in[12];
    const float* out_W  = (const float*)d_in[13];
    const float* out_b  = (const float*)d_in[14];

    float* out        = (float*)d_out;
    float* ws         = (float*)d_ws;
    float* out_logits = out;                 // V
    float* out_h      = out + V;             // H
    float* out_c      = out + V + H;         // H
    float* out_attnw  = out + V + 2 * H;     // L

    k_attn_whh<<<1040, 256, 0, stream>>>(tok, h0, emb, attn_W, attn_b, enc,
                                         W_hh, out_attnw, ws);
    k_a2d<<<1024, 384, 0, stream>>>(a2d_W, a2d_b, ws);
    k_lstm<<<1024, 256, 0, stream>>>(c0, W_ih, b_ih, b_hh, out_h, out_c, ws);
    k_vocab<<<NBLK5, 256, 0, stream>>>(out_W, out_b, out_logits, ws);
    k_final<<<256, 256, 0, stream>>>(out_logits, ws);
}

// Round 7
// 67.310 us; speedup vs baseline: 11.2204x; 1.1934x over previous
//
#include <hip/hip_runtime.h>
#include <math.h>

#define V 50257
#define H 1024
#define E 512
#define L 128
#define HE 1536            // H + E
#define NBLK5 2048         // blocks for vocab matvec -> 8192 waves
#define NWAVE5 (NBLK5 * 4)

// ws layout (floats)
#define WS_DECRAW 0        // 1536: [embed(512) | attn_out(1024)]
#define WS_DECIN  1536     // 1024: relu(a2d)
#define WS_HNEW   2560     // 1024: aligned copy of h_new
#define WS_ALOGIT 3584     // 128 : raw attention logits
#define WS_PAIRS  3712     // 2*NBLK5: (max, sumexp) per k_vocab block

__device__ __forceinline__ float wave_reduce_sum(float v) {
    #pragma unroll
    for (int off = 32; off > 0; off >>= 1) v += __shfl_xor(v, off, 64);
    return v;
}

// -------- K1a: attention logits. 128 blocks x 384 (block per row) --------
__global__ void k_attn_logits(const int* __restrict__ tok_p,
                              const float* __restrict__ h0,
                              const float* __restrict__ emb,
                              const float* __restrict__ attn_W,
                              const float* __restrict__ attn_b,
                              float* __restrict__ ws) {
    __shared__ __align__(16) float s_in[HE];
    __shared__ float s_part[6];
    const int tid = threadIdx.x;                 // 0..383
    const int tok = tok_p[0];
    for (int k = tid; k < HE; k += 384) {
        float v = (k < E) ? emb[(size_t)tok * E + k] : h0[k - E];
        s_in[k] = v;
        if (blockIdx.x == 0 && k < E) ws[WS_DECRAW + k] = v;
    }
    __syncthreads();
    const int lane = tid & 63, w = tid >> 6;     // w 0..5
    const int r = blockIdx.x;                    // 0..127
    const float4* s4 = (const float4*)s_in;
    const float4* w4 = (const float4*)(attn_W + (size_t)r * HE);
    float4 a = s4[lane + (w << 6)];
    float4 b = w4[lane + (w << 6)];
    float acc = a.x * b.x + a.y * b.y + a.z * b.z + a.w * b.w;
    acc = wave_reduce_sum(acc);
    if (lane == 0) s_part[w] = acc;
    __syncthreads();
    if (tid == 0) {
        float t = s_part[0] + s_part[1] + s_part[2] + s_part[3] + s_part[4] + s_part[5];
        ws[WS_ALOGIT + r] = t + attn_b[r];
    }
}

// -------- K1b: softmax + attn_out. 16 blocks x 256 (64 j's per block) -----
__global__ void k_attn_out(const float* __restrict__ enc,
                           float* __restrict__ out_attnw,
                           float* __restrict__ ws) {
    __shared__ float s_wn[L];
    __shared__ float s_acc[4][64];
    const int tid = threadIdx.x;
    if (tid < L) s_wn[tid] = ws[WS_ALOGIT + tid];
    __syncthreads();
    float m = -1e30f;
    #pragma unroll
    for (int l = 0; l < L; ++l) m = fmaxf(m, s_wn[l]);
    float s = 0.f;
    #pragma unroll
    for (int l = 0; l < L; ++l) s += __expf(s_wn[l] - m);
    __syncthreads();
    if (tid < L) {
        float wn = __expf(s_wn[tid] - m) / s;
        s_wn[tid] = wn;
        if (blockIdx.x == 0) out_attnw[tid] = wn;
    }
    __syncthreads();
    const int j = blockIdx.x * 64 + (tid & 63);
    const int lg = tid >> 6;                     // 0..3 -> l-range of 32
    float acc = 0.f;
    #pragma unroll
    for (int li = 0; li < 32; ++li) {
        const int l = (lg << 5) + li;
        acc = fmaf(s_wn[l], enc[l * H + j], acc);
    }
    s_acc[lg][tid & 63] = acc;
    __syncthreads();
    if (tid < 64) {
        float r = s_acc[0][tid] + s_acc[1][tid] + s_acc[2][tid] + s_acc[3][tid];
        ws[WS_DECRAW + E + blockIdx.x * 64 + tid] = r;
    }
}

// -------- K2: dec_in = relu(dec_in_raw @ a2d_W.T + b). 1024 blocks x 384 --
__global__ void k_a2d(const float* __restrict__ a2d_W,
                      const float* __restrict__ a2d_b,
                      float* __restrict__ ws) {
    __shared__ float s_part[6];
    const int tid = threadIdx.x, lane = tid & 63, w = tid >> 6;
    const int r = blockIdx.x;                    // 0..1023
    const float4* x4 = (const float4*)(ws + WS_DECRAW);
    const float4* w4 = (const float4*)(a2d_W + (size_t)r * HE);
    float4 a = x4[lane + (w << 6)];
    float4 b = w4[lane + (w << 6)];
    float acc = a.x * b.x + a.y * b.y + a.z * b.z + a.w * b.w;
    acc = wave_reduce_sum(acc);
    if (lane == 0) s_part[w] = acc;
    __syncthreads();
    if (tid == 0) {
        float t = s_part[0] + s_part[1] + s_part[2] + s_part[3] + s_part[4] + s_part[5];
        ws[WS_DECIN + r] = fmaxf(t + a2d_b[r], 0.f);
    }
}

// -------- K3: LSTM. 1024 blocks x 256, wave-per-gate, block-per-j ---------
__global__ void k_lstm(const float* __restrict__ h0,
                       const float* __restrict__ c0,
                       const float* __restrict__ W_ih,
                       const float* __restrict__ W_hh,
                       const float* __restrict__ b_ih,
                       const float* __restrict__ b_hh,
                       float* __restrict__ out_h,
                       float* __restrict__ out_c,
                       float* __restrict__ ws) {
    __shared__ float s_g[4];
    const int tid = threadIdx.x, lane = tid & 63, w = tid >> 6;   // w = gate
    const int j = blockIdx.x;                                     // 0..1023
    const float4* x4 = (const float4*)(ws + WS_DECIN);
    const float4* h4 = (const float4*)h0;
    const float4* wi4 = (const float4*)(W_ih + ((size_t)w * H + j) * H);
    const float4* wh4 = (const float4*)(W_hh + ((size_t)w * H + j) * H);
    float acc = 0.f;
    #pragma unroll
    for (int k = 0; k < 4; ++k) {
        float4 a = wi4[lane + (k << 6)];
        float4 x = x4[lane + (k << 6)];
        acc = fmaf(a.x, x.x, acc); acc = fmaf(a.y, x.y, acc);
        acc = fmaf(a.z, x.z, acc); acc = fmaf(a.w, x.w, acc);
        float4 b = wh4[lane + (k << 6)];
        float4 h = h4[lane + (k << 6)];
        acc = fmaf(b.x, h.x, acc); acc = fmaf(b.y, h.y, acc);
        acc = fmaf(b.z, h.z, acc); acc = fmaf(b.w, h.w, acc);
    }
    acc = wave_reduce_sum(acc);
    if (lane == 0) s_g[w] = acc;
    __syncthreads();
    if (tid == 0) {
        float gi_ = s_g[0] + b_ih[j]         + b_hh[j];
        float gf  = s_g[1] + b_ih[H + j]     + b_hh[H + j];
        float gg  = s_g[2] + b_ih[2 * H + j] + b_hh[2 * H + j];
        float go  = s_g[3] + b_ih[3 * H + j] + b_hh[3 * H + j];
        float si = 1.f / (1.f + expf(-gi_));
        float sf = 1.f / (1.f + expf(-gf));
        float so = 1.f / (1.f + expf(-go));
        float cn = sf * c0[j] + si * tanhf(gg);
        float hn = so * tanhf(cn);
        out_c[j] = cn;
        out_h[j] = hn;
        ws[WS_HNEW + j] = hn;
    }
}

// -------- K4: vocab matvec, 7 rows/wave, deep load pipeline ---------------
// Rows for wave gw: v_i = gw + i*8192. i=0..5 always valid (max 49151 < V);
// i=6 valid only for gw < 1105 (clamped load of row V-1 otherwise: L2-hot).
__global__ void k_vocab(const float* __restrict__ out_W,
                        const float* __restrict__ out_b,
                        float* __restrict__ logits,
                        float* __restrict__ ws) {
    const int lane = threadIdx.x & 63;
    const int widx = threadIdx.x >> 6;
    const int gw = (blockIdx.x << 2) + widx;          // 0..8191
    const float4* h4 = (const float4*)(ws + WS_HNEW);
    float4 hr[4];
    #pragma unroll
    for (int k = 0; k < 4; ++k) hr[k] = h4[lane + (k << 6)];

    const int v6 = gw + 6 * NWAVE5;
    const bool valid6 = (v6 < V);
    const int v6c = valid6 ? v6 : (V - 1);

    float lg[7];

    // ---- group A: rows 0..3, all 16 loads issued before any reduce -------
    float4 a[4][4];
    #pragma unroll
    for (int i = 0; i < 4; ++i) {
        const float4* w4 = (const float4*)(out_W + (size_t)(gw + i * NWAVE5) * H);
        #pragma unroll
        for (int k = 0; k < 4; ++k) a[i][k] = w4[lane + (k << 6)];
    }
    #pragma unroll
    for (int i = 0; i < 4; ++i) {
        float t = 0.f;
        #pragma unroll
        for (int k = 0; k < 4; ++k) {
            t = fmaf(a[i][k].x, hr[k].x, t); t = fmaf(a[i][k].y, hr[k].y, t);
            t = fmaf(a[i][k].z, hr[k].z, t); t = fmaf(a[i][k].w, hr[k].w, t);
        }
        t = wave_reduce_sum(t);
        lg[i] = t + out_b[gw + i * NWAVE5];
    }

    // ---- group B: rows 4,5,6(clamped), 12 loads issued before reduces ----
    float4 bfr[3][4];
    #pragma unroll
    for (int i = 0; i < 2; ++i) {
        const float4* w4 = (const float4*)(out_W + (size_t)(gw + (4 + i) * NWAVE5) * H);
        #pragma unroll
        for (int k = 0; k < 4; ++k) bfr[i][k] = w4[lane + (k << 6)];
    }
    {
        const float4* w4 = (const float4*)(out_W + (size_t)v6c * H);
        #pragma unroll
        for (int k = 0; k < 4; ++k) bfr[2][k] = w4[lane + (k << 6)];
    }
    #pragma unroll
    for (int i = 0; i < 3; ++i) {
        float t = 0.f;
        #pragma unroll
        for (int k = 0; k < 4; ++k) {
            t = fmaf(bfr[i][k].x, hr[k].x, t); t = fmaf(bfr[i][k].y, hr[k].y, t);
            t = fmaf(bfr[i][k].z, hr[k].z, t); t = fmaf(bfr[i][k].w, hr[k].w, t);
        }
        t = wave_reduce_sum(t);
        lg[4 + i] = t + out_b[(i < 2) ? (gw + (4 + i) * NWAVE5) : v6c];
    }
    if (!valid6) lg[6] = -1e30f;                  // excluded from max/sum

    // ---- stores + wave (max, sumexp) -------------------------------------
    if (lane == 0) {
        #pragma unroll
        for (int i = 0; i < 6; ++i) logits[gw + i * NWAVE5] = lg[i];
        if (valid6) logits[v6] = lg[6];
    }
    float m = lg[0];
    #pragma unroll
    for (int i = 1; i < 7; ++i) m = fmaxf(m, lg[i]);
    float s = 0.f;
    #pragma unroll
    for (int i = 0; i < 7; ++i) s += __expf(lg[i] - m);   // exp(-inf)=0 for invalid

    __shared__ float sm[4], ss[4];
    if (lane == 0) { sm[widx] = m; ss[widx] = s; }
    __syncthreads();
    if (threadIdx.x == 0) {
        float M = sm[0], S = ss[0];
        #pragma unroll
        for (int i = 1; i < 4; ++i) {
            float Mn = fmaxf(M, sm[i]);
            S = S * __expf(M - Mn) + ss[i] * __expf(sm[i] - Mn);
            M = Mn;
        }
        ws[WS_PAIRS + 2 * blockIdx.x]     = M;
        ws[WS_PAIRS + 2 * blockIdx.x + 1] = S;
    }
}

// -------- K5: fold partials + finalize log-softmax ------------------------
__global__ void k_final(float* __restrict__ logits,
                        const float* __restrict__ ws) {
    __shared__ float sm[256], ss[256];
    const int tid = threadIdx.x;
    float M = -1e30f, S = 0.f;
    for (int i = tid; i < NBLK5; i += 256) {
        float m2 = ws[WS_PAIRS + 2 * i], s2 = ws[WS_PAIRS + 2 * i + 1];
        float Mn = fmaxf(M, m2);
        S = S * __expf(M - Mn) + s2 * __expf(m2 - Mn);
        M = Mn;
    }
    sm[tid] = M; ss[tid] = S;
    __syncthreads();
    for (int off = 128; off > 0; off >>= 1) {
        if (tid < off) {
            float m2 = sm[tid + off], s2 = ss[tid + off];
            float Mn = fmaxf(sm[tid], m2);
            ss[tid] = ss[tid] * __expf(sm[tid] - Mn) + s2 * __expf(m2 - Mn);
            sm[tid] = Mn;
        }
        __syncthreads();
    }
    const float C = sm[0] + logf(ss[0]);
    for (int v = blockIdx.x * 256 + tid; v < V; v += gridDim.x * 256)
        logits[v] -= C;
}

extern "C" void kernel_launch(void* const* d_in, const int* in_sizes, int n_in,
                              void* d_out, int out_size, void* d_ws, size_t ws_size,
                              hipStream_t stream) {
    const int*   tok    = (const int*)d_in[0];
    const float* h0     = (const float*)d_in[1];
    const float* c0     = (const float*)d_in[2];
    const float* enc    = (const float*)d_in[3];
    const float* emb    = (const float*)d_in[4];
    const float* attn_W = (const float*)d_in[5];
    const float* attn_b = (const float*)d_in[6];
    const float* a2d_W  = (const float*)d_in[7];
    const float* a2d_b  = (const float*)d_in[8];
    const float* W_ih   = (const float*)d_in[9];
    const float* W_hh   = (const float*)d_in[10];
    const float* b_ih   = (const float*)d_in[11];
    const float* b_hh   = (const float*)d_in[12];
    const float* out_W  = (const float*)d_in[13];
    const float* out_b  = (const float*)d_in[14];

    float* out        = (float*)d_out;
    float* ws         = (float*)d_ws;
    float* out_logits = out;                 // V
    float* out_h      = out + V;             // H
    float* out_c      = out + V + H;         // H
    float* out_attnw  = out + V + 2 * H;     // L

    k_attn_logits<<<128, 384, 0, stream>>>(tok, h0, emb, attn_W, attn_b, ws);
    k_attn_out<<<16, 256, 0, stream>>>(enc, out_attnw, ws);
    k_a2d<<<1024, 384, 0, stream>>>(a2d_W, a2d_b, ws);
    k_lstm<<<1024, 256, 0, stream>>>(h0, c0, W_ih, W_hh, b_ih, b_hh, out_h, out_c, ws);
    k_vocab<<<NBLK5, 256, 0, stream>>>(out_W, out_b, out_logits, ws);
    k_final<<<256, 256, 0, stream>>>(out_logits, ws);
}

// Round 8
// 65.664 us; speedup vs baseline: 11.5016x; 1.0251x over previous
//
#include <hip/hip_runtime.h>
#include <math.h>

#define V 50257
#define H 1024
#define E 512
#define L 128
#define HE 1536            // H + E
#define NBLK5 2048         // blocks for vocab matvec -> 8192 waves
#define VSTRIDE (NBLK5 * 4)

// ws layout (floats)
#define WS_DECRAW 0        // 1536: [embed(512) | attn_out(1024)]
#define WS_DECIN  1536     // 1024: relu(a2d)
#define WS_HNEW   2560     // 1024: aligned copy of h_new
#define WS_GHH    3584     // 4096: W_hh @ h0, gate-major
#define WS_ALOGIT 7680     // 128 : raw attention logits
#define WS_PAIRS  7808     // 2*NBLK5: (max, sumexp) per k_vocab block

__device__ __forceinline__ float wave_reduce_sum(float v) {
    #pragma unroll
    for (int off = 32; off > 0; off >>= 1) v += __shfl_xor(v, off, 64);
    return v;
}

// -------- K1: blocks 0..127 attention logits; 128..1151 W_hh@h0 -----------
__global__ __launch_bounds__(256)
void k_attn_whh(const int* __restrict__ tok_p,
                const float* __restrict__ h0,
                const float* __restrict__ emb,
                const float* __restrict__ attn_W,
                const float* __restrict__ attn_b,
                const float* __restrict__ W_hh,
                float* __restrict__ ws) {
    const int tid = threadIdx.x, lane = tid & 63, w = tid >> 6;
    const int bid = blockIdx.x;

    if (bid >= 128) {
        // ghh[w*H + j] = dot(W_hh[w*H + j], h0); j = bid-128, wave w = gate
        const int j = bid - 128;                   // 0..1023
        const float4* h4 = (const float4*)h0;
        const float4* wh4 = (const float4*)(W_hh + ((size_t)w * H + j) * H);
        float acc = 0.f;
        #pragma unroll
        for (int k = 0; k < 4; ++k) {
            float4 b = wh4[lane + (k << 6)];
            float4 h = h4[lane + (k << 6)];
            acc = fmaf(b.x, h.x, acc); acc = fmaf(b.y, h.y, acc);
            acc = fmaf(b.z, h.z, acc); acc = fmaf(b.w, h.w, acc);
        }
        acc = wave_reduce_sum(acc);
        if (lane == 0) ws[WS_GHH + w * H + j] = acc;
        return;
    }

    // attention logits: block per row r = bid (same 128-block parallelism as R3)
    __shared__ float s_in[HE];
    __shared__ float s_part[4];
    const int tok = tok_p[0];
    for (int k = tid; k < HE; k += 256) {
        float v = (k < E) ? emb[(size_t)tok * E + k] : h0[k - E];
        s_in[k] = v;
        if (bid == 0 && k < E) ws[WS_DECRAW + k] = v;   // embed slice
    }
    __syncthreads();
    const float* wr = attn_W + (size_t)bid * HE;
    float acc = 0.f;
    #pragma unroll
    for (int i = 0; i < 6; ++i)
        acc = fmaf(s_in[tid + (i << 8)], wr[tid + (i << 8)], acc);
    acc = wave_reduce_sum(acc);
    if (lane == 0) s_part[w] = acc;
    __syncthreads();
    if (tid == 0)
        ws[WS_ALOGIT + bid] = s_part[0] + s_part[1] + s_part[2] + s_part[3]
                              + attn_b[bid];
}

// -------- K2: softmax + attn_out. 16 blocks x 256 (64 j's per block) ------
__global__ void k_attn_out(const float* __restrict__ enc,
                           float* __restrict__ out_attnw,
                           float* __restrict__ ws) {
    __shared__ float s_wn[L];
    __shared__ float s_acc[4][64];
    const int tid = threadIdx.x;
    if (tid < L) s_wn[tid] = ws[WS_ALOGIT + tid];
    __syncthreads();
    float m = -1e30f;
    #pragma unroll
    for (int l = 0; l < L; ++l) m = fmaxf(m, s_wn[l]);
    float s = 0.f;
    #pragma unroll
    for (int l = 0; l < L; ++l) s += __expf(s_wn[l] - m);
    __syncthreads();
    if (tid < L) {
        float wn = __expf(s_wn[tid] - m) / s;
        s_wn[tid] = wn;
        if (blockIdx.x == 0) out_attnw[tid] = wn;
    }
    __syncthreads();
    const int j = blockIdx.x * 64 + (tid & 63);
    const int lg = tid >> 6;                     // 0..3 -> l-range of 32
    float acc = 0.f;
    #pragma unroll
    for (int li = 0; li < 32; ++li) {
        const int l = (lg << 5) + li;
        acc = fmaf(s_wn[l], enc[l * H + j], acc);
    }
    s_acc[lg][tid & 63] = acc;
    __syncthreads();
    if (tid < 64) {
        float r = s_acc[0][tid] + s_acc[1][tid] + s_acc[2][tid] + s_acc[3][tid];
        ws[WS_DECRAW + E + blockIdx.x * 64 + tid] = r;
    }
}

// -------- K3: dec_in = relu(dec_in_raw @ a2d_W.T + b). 1024 blocks x 384 --
__global__ void k_a2d(const float* __restrict__ a2d_W,
                      const float* __restrict__ a2d_b,
                      float* __restrict__ ws) {
    __shared__ float s_part[6];
    const int tid = threadIdx.x, lane = tid & 63, w = tid >> 6;
    const int r = blockIdx.x;                    // 0..1023
    const float4* x4 = (const float4*)(ws + WS_DECRAW);
    const float4* w4 = (const float4*)(a2d_W + (size_t)r * HE);
    float4 a = x4[lane + (w << 6)];
    float4 b = w4[lane + (w << 6)];
    float acc = a.x * b.x + a.y * b.y + a.z * b.z + a.w * b.w;
    acc = wave_reduce_sum(acc);
    if (lane == 0) s_part[w] = acc;
    __syncthreads();
    if (tid == 0) {
        float t = s_part[0] + s_part[1] + s_part[2] + s_part[3] + s_part[4] + s_part[5];
        ws[WS_DECIN + r] = fmaxf(t + a2d_b[r], 0.f);
    }
}

// -------- K4: LSTM, W_ih half only; ghh precomputed. 1024 blocks x 256 ----
__global__ void k_lstm(const float* __restrict__ c0,
                       const float* __restrict__ W_ih,
                       const float* __restrict__ b_ih,
                       const float* __restrict__ b_hh,
                       float* __restrict__ out_h,
                       float* __restrict__ out_c,
                       float* __restrict__ ws) {
    __shared__ float s_g[4];
    const int tid = threadIdx.x, lane = tid & 63, w = tid >> 6;   // w = gate
    const int j = blockIdx.x;                                     // 0..1023
    const float4* x4 = (const float4*)(ws + WS_DECIN);
    const float4* wi4 = (const float4*)(W_ih + ((size_t)w * H + j) * H);
    float acc = 0.f;
    #pragma unroll
    for (int k = 0; k < 4; ++k) {
        float4 a = wi4[lane + (k << 6)];
        float4 x = x4[lane + (k << 6)];
        acc = fmaf(a.x, x.x, acc); acc = fmaf(a.y, x.y, acc);
        acc = fmaf(a.z, x.z, acc); acc = fmaf(a.w, x.w, acc);
    }
    acc = wave_reduce_sum(acc);
    if (lane == 0) s_g[w] = acc + ws[WS_GHH + w * H + j];
    __syncthreads();
    if (tid == 0) {
        float gi_ = s_g[0] + b_ih[j]         + b_hh[j];
        float gf  = s_g[1] + b_ih[H + j]     + b_hh[H + j];
        float gg  = s_g[2] + b_ih[2 * H + j] + b_hh[2 * H + j];
        float go  = s_g[3] + b_ih[3 * H + j] + b_hh[3 * H + j];
        float si = 1.f / (1.f + expf(-gi_));
        float sf = 1.f / (1.f + expf(-gf));
        float so = 1.f / (1.f + expf(-go));
        float cn = sf * c0[j] + si * tanhf(gg);
        float hn = so * tanhf(cn);
        out_c[j] = cn;
        out_h[j] = hn;
        ws[WS_HNEW + j] = hn;
    }
}

// -------- K5: vocab matvec, 2 rows in flight per wave (R3-verified) -------
__global__ void k_vocab(const float* __restrict__ out_W,
                        const float* __restrict__ out_b,
                        float* __restrict__ logits,
                        float* __restrict__ ws) {
    const int lane = threadIdx.x & 63;
    const int widx = threadIdx.x >> 6;
    const int gw = (blockIdx.x << 2) + widx;          // 0..8191
    const float4* h4 = (const float4*)(ws + WS_HNEW);
    float4 hr[4];
    #pragma unroll
    for (int k = 0; k < 4; ++k) hr[k] = h4[lane + (k << 6)];
    float m = -1e30f, s = 0.f;
    for (int v = gw; v < V; v += 2 * VSTRIDE) {
        const int v2 = v + VSTRIDE;
        const float4* w0 = (const float4*)(out_W + (size_t)v * H);
        float acc0 = 0.f, acc1 = 0.f;
        #pragma unroll
        for (int k = 0; k < 4; ++k) {
            float4 a = w0[lane + (k << 6)];
            acc0 = fmaf(hr[k].x, a.x, acc0); acc0 = fmaf(hr[k].y, a.y, acc0);
            acc0 = fmaf(hr[k].z, a.z, acc0); acc0 = fmaf(hr[k].w, a.w, acc0);
        }
        if (v2 < V) {
            const float4* w1 = (const float4*)(out_W + (size_t)v2 * H);
            #pragma unroll
            for (int k = 0; k < 4; ++k) {
                float4 a = w1[lane + (k << 6)];
                acc1 = fmaf(hr[k].x, a.x, acc1); acc1 = fmaf(hr[k].y, a.y, acc1);
                acc1 = fmaf(hr[k].z, a.z, acc1); acc1 = fmaf(hr[k].w, a.w, acc1);
            }
        }
        acc0 = wave_reduce_sum(acc0);
        float l0 = acc0 + out_b[v];
        if (lane == 0) logits[v] = l0;
        float mo = m;
        m = fmaxf(m, l0);
        s = s * __expf(mo - m) + __expf(l0 - m);
        if (v2 < V) {
            acc1 = wave_reduce_sum(acc1);
            float l1 = acc1 + out_b[v2];
            if (lane == 0) logits[v2] = l1;
            mo = m;
            m = fmaxf(m, l1);
            s = s * __expf(mo - m) + __expf(l1 - m);
        }
    }
    __shared__ float sm[4], ss[4];
    if (lane == 0) { sm[widx] = m; ss[widx] = s; }
    __syncthreads();
    if (threadIdx.x == 0) {
        float M = sm[0], S = ss[0];
        #pragma unroll
        for (int i = 1; i < 4; ++i) {
            float Mn = fmaxf(M, sm[i]);
            S = S * __expf(M - Mn) + ss[i] * __expf(sm[i] - Mn);
            M = Mn;
        }
        ws[WS_PAIRS + 2 * blockIdx.x]     = M;
        ws[WS_PAIRS + 2 * blockIdx.x + 1] = S;
    }
}

// -------- K6: fold partials + finalize log-softmax ------------------------
__global__ void k_final(float* __restrict__ logits,
                        const float* __restrict__ ws) {
    __shared__ float sm[256], ss[256];
    const int tid = threadIdx.x;
    float M = -1e30f, S = 0.f;
    for (int i = tid; i < NBLK5; i += 256) {
        float m2 = ws[WS_PAIRS + 2 * i], s2 = ws[WS_PAIRS + 2 * i + 1];
        float Mn = fmaxf(M, m2);
        S = S * __expf(M - Mn) + s2 * __expf(m2 - Mn);
        M = Mn;
    }
    sm[tid] = M; ss[tid] = S;
    __syncthreads();
    for (int off = 128; off > 0; off >>= 1) {
        if (tid < off) {
            float m2 = sm[tid + off], s2 = ss[tid + off];
            float Mn = fmaxf(sm[tid], m2);
            ss[tid] = ss[tid] * __expf(sm[tid] - Mn) + s2 * __expf(m2 - Mn);
            sm[tid] = Mn;
        }
        __syncthreads();
    }
    const float C = sm[0] + logf(ss[0]);
    for (int v = blockIdx.x * 256 + tid; v < V; v += gridDim.x * 256)
        logits[v] -= C;
}

extern "C" void kernel_launch(void* const* d_in, const int* in_sizes, int n_in,
                              void* d_out, int out_size, void* d_ws, size_t ws_size,
                              hipStream_t stream) {
    const int*   tok    = (const int*)d_in[0];
    const float* h0     = (const float*)d_in[1];
    const float* c0     = (const float*)d_in[2];
    const float* enc    = (const float*)d_in[3];
    const float* emb    = (const float*)d_in[4];
    const float* attn_W = (const float*)d_in[5];
    const float* attn_b = (const float*)d_in[6];
    const float* a2d_W  = (const float*)d_in[7];
    const float* a2d_b  = (const float*)d_in[8];
    const float* W_ih   = (const float*)d_in[9];
    const float* W_hh   = (const float*)d_in[10];
    const float* b_ih   = (const float*)d_in[11];
    const float* b_hh   = (const float*)d_in[12];
    const float* out_W  = (const float*)d_in[13];
    const float* out_b  = (const float*)d_in[14];

    float* out        = (float*)d_out;
    float* ws         = (float*)d_ws;
    float* out_logits = out;                 // V
    float* out_h      = out + V;             // H
    float* out_c      = out + V + H;         // H
    float* out_attnw  = out + V + 2 * H;     // L

    k_attn_whh<<<1152, 256, 0, stream>>>(tok, h0, emb, attn_W, attn_b, W_hh, ws);
    k_attn_out<<<16, 256, 0, stream>>>(enc, out_attnw, ws);
    k_a2d<<<1024, 384, 0, stream>>>(a2d_W, a2d_b, ws);
    k_lstm<<<1024, 256, 0, stream>>>(c0, W_ih, b_ih, b_hh, out_h, out_c, ws);
    k_vocab<<<NBLK5, 256, 0, stream>>>(out_W, out_b, out_logits, ws);
    k_final<<<256, 256, 0, stream>>>(out_logits, ws);
}

// Round 9
// 64.303 us; speedup vs baseline: 11.7451x; 1.0212x over previous
//
#include <hip/hip_runtime.h>
#include <math.h>

#define V 50257
#define H 1024
#define E 512
#define L 128
#define HE 1536            // H + E
#define NBLK5 2048         // blocks for vocab matvec -> 8192 waves
#define NWAVE5 (NBLK5 * 4)

// ws layout (floats)
#define WS_DECRAW 0        // 1536: [embed(512) | attn_out(1024)]
#define WS_DECIN  1536     // 1024: relu(a2d)
#define WS_HNEW   2560     // 1024: aligned copy of h_new
#define WS_GHH    3584     // 4096: W_hh @ h0, gate-major
#define WS_ALOGIT 7680     // 128 : raw attention logits
#define WS_PAIRS  7808     // 2*NBLK5: (max, sumexp) per k_vocab block

__device__ __forceinline__ float wave_reduce_sum(float v) {
    #pragma unroll
    for (int off = 32; off > 0; off >>= 1) v += __shfl_xor(v, off, 64);
    return v;
}

// -------- K1: blocks 0..127 attention logits; 128..1151 W_hh@h0 -----------
__global__ __launch_bounds__(256)
void k_attn_whh(const int* __restrict__ tok_p,
                const float* __restrict__ h0,
                const float* __restrict__ emb,
                const float* __restrict__ attn_W,
                const float* __restrict__ attn_b,
                const float* __restrict__ W_hh,
                float* __restrict__ ws) {
    const int tid = threadIdx.x, lane = tid & 63, w = tid >> 6;
    const int bid = blockIdx.x;

    if (bid >= 128) {
        const int j = bid - 128;                   // 0..1023
        const float4* h4 = (const float4*)h0;
        const float4* wh4 = (const float4*)(W_hh + ((size_t)w * H + j) * H);
        float acc = 0.f;
        #pragma unroll
        for (int k = 0; k < 4; ++k) {
            float4 b = wh4[lane + (k << 6)];
            float4 h = h4[lane + (k << 6)];
            acc = fmaf(b.x, h.x, acc); acc = fmaf(b.y, h.y, acc);
            acc = fmaf(b.z, h.z, acc); acc = fmaf(b.w, h.w, acc);
        }
        acc = wave_reduce_sum(acc);
        if (lane == 0) ws[WS_GHH + w * H + j] = acc;
        return;
    }

    __shared__ float s_in[HE];
    __shared__ float s_part[4];
    const int tok = tok_p[0];
    for (int k = tid; k < HE; k += 256) {
        float v = (k < E) ? emb[(size_t)tok * E + k] : h0[k - E];
        s_in[k] = v;
        if (bid == 0 && k < E) ws[WS_DECRAW + k] = v;   // embed slice
    }
    __syncthreads();
    const float* wr = attn_W + (size_t)bid * HE;
    float acc = 0.f;
    #pragma unroll
    for (int i = 0; i < 6; ++i)
        acc = fmaf(s_in[tid + (i << 8)], wr[tid + (i << 8)], acc);
    acc = wave_reduce_sum(acc);
    if (lane == 0) s_part[w] = acc;
    __syncthreads();
    if (tid == 0)
        ws[WS_ALOGIT + bid] = s_part[0] + s_part[1] + s_part[2] + s_part[3]
                              + attn_b[bid];
}

// -------- K2: softmax + attn_out. 16 blocks x 256 (64 j's per block) ------
__global__ void k_attn_out(const float* __restrict__ enc,
                           float* __restrict__ out_attnw,
                           float* __restrict__ ws) {
    __shared__ float s_wn[L];
    __shared__ float s_acc[4][64];
    const int tid = threadIdx.x;
    if (tid < L) s_wn[tid] = ws[WS_ALOGIT + tid];
    __syncthreads();
    float m = -1e30f;
    #pragma unroll
    for (int l = 0; l < L; ++l) m = fmaxf(m, s_wn[l]);
    float s = 0.f;
    #pragma unroll
    for (int l = 0; l < L; ++l) s += __expf(s_wn[l] - m);
    __syncthreads();
    if (tid < L) {
        float wn = __expf(s_wn[tid] - m) / s;
        s_wn[tid] = wn;
        if (blockIdx.x == 0) out_attnw[tid] = wn;
    }
    __syncthreads();
    const int j = blockIdx.x * 64 + (tid & 63);
    const int lg = tid >> 6;                     // 0..3 -> l-range of 32
    float acc = 0.f;
    #pragma unroll
    for (int li = 0; li < 32; ++li) {
        const int l = (lg << 5) + li;
        acc = fmaf(s_wn[l], enc[l * H + j], acc);
    }
    s_acc[lg][tid & 63] = acc;
    __syncthreads();
    if (tid < 64) {
        float r = s_acc[0][tid] + s_acc[1][tid] + s_acc[2][tid] + s_acc[3][tid];
        ws[WS_DECRAW + E + blockIdx.x * 64 + tid] = r;
    }
}

// -------- K3: dec_in = relu(dec_in_raw @ a2d_W.T + b). 1024 blocks x 384 --
__global__ void k_a2d(const float* __restrict__ a2d_W,
                      const float* __restrict__ a2d_b,
                      float* __restrict__ ws) {
    __shared__ float s_part[6];
    const int tid = threadIdx.x, lane = tid & 63, w = tid >> 6;
    const int r = blockIdx.x;                    // 0..1023
    const float4* x4 = (const float4*)(ws + WS_DECRAW);
    const float4* w4 = (const float4*)(a2d_W + (size_t)r * HE);
    float4 a = x4[lane + (w << 6)];
    float4 b = w4[lane + (w << 6)];
    float acc = a.x * b.x + a.y * b.y + a.z * b.z + a.w * b.w;
    acc = wave_reduce_sum(acc);
    if (lane == 0) s_part[w] = acc;
    __syncthreads();
    if (tid == 0) {
        float t = s_part[0] + s_part[1] + s_part[2] + s_part[3] + s_part[4] + s_part[5];
        ws[WS_DECIN + r] = fmaxf(t + a2d_b[r], 0.f);
    }
}

// -------- K4: LSTM, W_ih half only; ghh precomputed. 1024 blocks x 256 ----
__global__ void k_lstm(const float* __restrict__ c0,
                       const float* __restrict__ W_ih,
                       const float* __restrict__ b_ih,
                       const float* __restrict__ b_hh,
                       float* __restrict__ out_h,
                       float* __restrict__ out_c,
                       float* __restrict__ ws) {
    __shared__ float s_g[4];
    const int tid = threadIdx.x, lane = tid & 63, w = tid >> 6;   // w = gate
    const int j = blockIdx.x;                                     // 0..1023
    const float4* x4 = (const float4*)(ws + WS_DECIN);
    const float4* wi4 = (const float4*)(W_ih + ((size_t)w * H + j) * H);
    float acc = 0.f;
    #pragma unroll
    for (int k = 0; k < 4; ++k) {
        float4 a = wi4[lane + (k << 6)];
        float4 x = x4[lane + (k << 6)];
        acc = fmaf(a.x, x.x, acc); acc = fmaf(a.y, x.y, acc);
        acc = fmaf(a.z, x.z, acc); acc = fmaf(a.w, x.w, acc);
    }
    acc = wave_reduce_sum(acc);
    if (lane == 0) s_g[w] = acc + ws[WS_GHH + w * H + j];
    __syncthreads();
    if (tid == 0) {
        float gi_ = s_g[0] + b_ih[j]         + b_hh[j];
        float gf  = s_g[1] + b_ih[H + j]     + b_hh[H + j];
        float gg  = s_g[2] + b_ih[2 * H + j] + b_hh[2 * H + j];
        float go  = s_g[3] + b_ih[3 * H + j] + b_hh[3 * H + j];
        float si = 1.f / (1.f + expf(-gi_));
        float sf = 1.f / (1.f + expf(-gf));
        float so = 1.f / (1.f + expf(-go));
        float cn = sf * c0[j] + si * tanhf(gg);
        float hn = so * tanhf(cn);
        out_c[j] = cn;
        out_h[j] = hn;
        ws[WS_HNEW + j] = hn;
    }
}

// -------- K5: vocab matvec, 2-row groups, 2-stage software pipeline -------
// Wave gw handles rows v_i = gw + i*8192, i=0..6 (i<=5 always valid; i=6
// valid iff gw < 1105, else clamped to row V-1 -> L2-broadcast, excluded).
__global__ void k_vocab(const float* __restrict__ out_W,
                        const float* __restrict__ out_b,
                        float* __restrict__ logits,
                        float* __restrict__ ws) {
    const int lane = threadIdx.x & 63;
    const int widx = threadIdx.x >> 6;
    const int gw = (blockIdx.x << 2) + widx;          // 0..8191
    const float4* h4 = (const float4*)(ws + WS_HNEW);
    float4 hr[4];
    #pragma unroll
    for (int k = 0; k < 4; ++k) hr[k] = h4[lane + (k << 6)];

    const int v6 = gw + 6 * NWAVE5;
    const bool valid6 = (v6 < V);
    const int v6c = valid6 ? v6 : (V - 1);

    float4 A[8], B[8];
    float m = -1e30f, s = 0.f;
    float lg[7];

    #define LOAD2(dst, va, vb)                                                \
        {                                                                     \
            const float4* p0 = (const float4*)(out_W + (size_t)(va) * H);     \
            const float4* p1 = (const float4*)(out_W + (size_t)(vb) * H);     \
            _Pragma("unroll")                                                 \
            for (int k = 0; k < 4; ++k) {                                     \
                dst[k]     = p0[lane + (k << 6)];                             \
                dst[4 + k] = p1[lane + (k << 6)];                             \
            }                                                                 \
        }
    #define RED2(src, i0, i1)                                                 \
        {                                                                     \
            float t0 = 0.f, t1 = 0.f;                                         \
            _Pragma("unroll")                                                 \
            for (int k = 0; k < 4; ++k) {                                     \
                t0 = fmaf(src[k].x, hr[k].x, t0);                             \
                t0 = fmaf(src[k].y, hr[k].y, t0);                             \
                t0 = fmaf(src[k].z, hr[k].z, t0);                             \
                t0 = fmaf(src[k].w, hr[k].w, t0);                             \
                t1 = fmaf(src[4 + k].x, hr[k].x, t1);                         \
                t1 = fmaf(src[4 + k].y, hr[k].y, t1);                         \
                t1 = fmaf(src[4 + k].z, hr[k].z, t1);                         \
                t1 = fmaf(src[4 + k].w, hr[k].w, t1);                         \
            }                                                                 \
            t0 = wave_reduce_sum(t0);                                         \
            t1 = wave_reduce_sum(t1);                                         \
            lg[i0] = t0 + out_b[gw + (i0) * NWAVE5];                          \
            lg[i1] = t1 + out_b[gw + (i1) * NWAVE5];                          \
            float mo = m;                                                     \
            m = fmaxf(m, fmaxf(lg[i0], lg[i1]));                              \
            s = s * __expf(mo - m) + __expf(lg[i0] - m) + __expf(lg[i1] - m); \
        }

    LOAD2(A, gw, gw + NWAVE5);                    // rows 0,1 in flight
    LOAD2(B, gw + 2 * NWAVE5, gw + 3 * NWAVE5);   // rows 2,3 in flight
    RED2(A, 0, 1);                                // reduce 0,1 (B in flight)
    LOAD2(A, gw + 4 * NWAVE5, gw + 5 * NWAVE5);   // rows 4,5 in flight
    RED2(B, 2, 3);                                // reduce 2,3 (A in flight)
    {                                             // row 6 (clamped) in flight
        const float4* p0 = (const float4*)(out_W + (size_t)v6c * H);
        #pragma unroll
        for (int k = 0; k < 4; ++k) B[k] = p0[lane + (k << 6)];
    }
    RED2(A, 4, 5);                                // reduce 4,5 (B in flight)
    {                                             // reduce row 6
        float t0 = 0.f;
        #pragma unroll
        for (int k = 0; k < 4; ++k) {
            t0 = fmaf(B[k].x, hr[k].x, t0); t0 = fmaf(B[k].y, hr[k].y, t0);
            t0 = fmaf(B[k].z, hr[k].z, t0); t0 = fmaf(B[k].w, hr[k].w, t0);
        }
        t0 = wave_reduce_sum(t0);
        lg[6] = t0 + out_b[v6c];
        if (valid6) {
            float mo = m;
            m = fmaxf(m, lg[6]);
            s = s * __expf(mo - m) + __expf(lg[6] - m);
        }
    }
    #undef LOAD2
    #undef RED2

    if (lane == 0) {
        #pragma unroll
        for (int i = 0; i < 6; ++i) logits[gw + i * NWAVE5] = lg[i];
        if (valid6) logits[v6] = lg[6];
    }

    __shared__ float sm[4], ss[4];
    if (lane == 0) { sm[widx] = m; ss[widx] = s; }
    __syncthreads();
    if (threadIdx.x == 0) {
        float M = sm[0], S = ss[0];
        #pragma unroll
        for (int i = 1; i < 4; ++i) {
            float Mn = fmaxf(M, sm[i]);
            S = S * __expf(M - Mn) + ss[i] * __expf(sm[i] - Mn);
            M = Mn;
        }
        ws[WS_PAIRS + 2 * blockIdx.x]     = M;
        ws[WS_PAIRS + 2 * blockIdx.x + 1] = S;
    }
}

// -------- K6: fold partials + finalize log-softmax ------------------------
__global__ void k_final(float* __restrict__ logits,
                        const float* __restrict__ ws) {
    __shared__ float sm[256], ss[256];
    const int tid = threadIdx.x;
    float M = -1e30f, S = 0.f;
    for (int i = tid; i < NBLK5; i += 256) {
        float m2 = ws[WS_PAIRS + 2 * i], s2 = ws[WS_PAIRS + 2 * i + 1];
        float Mn = fmaxf(M, m2);
        S = S * __expf(M - Mn) + s2 * __expf(m2 - Mn);
        M = Mn;
    }
    sm[tid] = M; ss[tid] = S;
    __syncthreads();
    for (int off = 128; off > 0; off >>= 1) {
        if (tid < off) {
            float m2 = sm[tid + off], s2 = ss[tid + off];
            float Mn = fmaxf(sm[tid], m2);
            ss[tid] = ss[tid] * __expf(sm[tid] - Mn) + s2 * __expf(m2 - Mn);
            sm[tid] = Mn;
        }
        __syncthreads();
    }
    const float C = sm[0] + logf(ss[0]);
    for (int v = blockIdx.x * 256 + tid; v < V; v += gridDim.x * 256)
        logits[v] -= C;
}

extern "C" void kernel_launch(void* const* d_in, const int* in_sizes, int n_in,
                              void* d_out, int out_size, void* d_ws, size_t ws_size,
                              hipStream_t stream) {
    const int*   tok    = (const int*)d_in[0];
    const float* h0     = (const float*)d_in[1];
    const float* c0     = (const float*)d_in[2];
    const float* enc    = (const float*)d_in[3];
    const float* emb    = (const float*)d_in[4];
    const float* attn_W = (const float*)d_in[5];
    const float* attn_b = (const float*)d_in[6];
    const float* a2d_W  = (const float*)d_in[7];
    const float* a2d_b  = (const float*)d_in[8];
    const float* W_ih   = (const float*)d_in[9];
    const float* W_hh   = (const float*)d_in[10];
    const float* b_ih   = (const float*)d_in[11];
    const float* b_hh   = (const float*)d_in[12];
    const float* out_W  = (const float*)d_in[13];
    const float* out_b  = (const float*)d_in[14];

    float* out        = (float*)d_out;
    float* ws         = (float*)d_ws;
    float* out_logits = out;                 // V
    float* out_h      = out + V;             // H
    float* out_c      = out + V + H;         // H
    float* out_attnw  = out + V + 2 * H;     // L

    k_attn_whh<<<1152, 256, 0, stream>>>(tok, h0, emb, attn_W, attn_b, W_hh, ws);
    k_attn_out<<<16, 256, 0, stream>>>(enc, out_attnw, ws);
    k_a2d<<<1024, 384, 0, stream>>>(a2d_W, a2d_b, ws);
    k_lstm<<<1024, 256, 0, stream>>>(c0, W_ih, b_ih, b_hh, out_h, out_c, ws);
    k_vocab<<<NBLK5, 256, 0, stream>>>(out_W, out_b, out_logits, ws);
    k_final<<<256, 256, 0, stream>>>(out_logits, ws);
}